// Round 18
// baseline (530.743 us; speedup 1.0000x reference)
//
#include <hip/hip_runtime.h>
#include <hip/hip_bf16.h>
#include <stdint.h>

typedef __attribute__((ext_vector_type(4))) float f32x4;
typedef __bf16 bfv8 __attribute__((ext_vector_type(8)));
typedef unsigned short u16x8 __attribute__((ext_vector_type(8)));
typedef unsigned short u16x4 __attribute__((ext_vector_type(4)));

#define DEV static __device__ __forceinline__

DEV float b2f(unsigned short h) {
    unsigned u = ((unsigned)h) << 16;
    return __builtin_bit_cast(float, u);
}
DEV unsigned short f2b(float f) {  // cold paths only
    unsigned u = __builtin_bit_cast(unsigned, f);
    u += 0x7fffu + ((u >> 16) & 1u);
    return (unsigned short)(u >> 16);
}
DEV unsigned short f2bn(float f) {
    return __builtin_bit_cast(unsigned short, (__bf16)f);
}
DEV bfv8 ldb8(const unsigned short* p) {
    return __builtin_bit_cast(bfv8, *(const u16x8*)p);
}
DEV void stb4(unsigned short* p, f32x4 v) {
    u16x4 o;
    o[0] = f2bn(v[0]); o[1] = f2bn(v[1]); o[2] = f2bn(v[2]); o[3] = f2bn(v[3]);
    *(u16x4*)p = o;
}

// B=8, H=W=224, C=96, WS=7, SS=3, NH=3, HD=32, N=49, nW=1024, B_=8192
static constexpr int T = 401408;  // B_ * N tokens

// ---------------------------------------------------------------------------
// K0: one-shot prep: fp32->bf16 weights + combined rel-pos-bias/shift-mask table.
__global__ __launch_bounds__(256) void k_prep(const float* __restrict__ qkvw,
                                              const float* __restrict__ projw,
                                              const float* __restrict__ w1,
                                              const float* __restrict__ w2,
                                              const float* __restrict__ rpb,
                                              const float* __restrict__ mask,
                                              unsigned short* __restrict__ wb,
                                              float* __restrict__ cmb) {
    int i = blockIdx.x * 256 + threadIdx.x;
    if (i < 110592) {
        float v;
        if (i < 27648) v = qkvw[i];
        else if (i < 36864) v = projw[i - 27648];
        else if (i < 73728) v = w1[i - 36864];
        else v = w2[i - 73728];
        wb[i] = f2b(v);
    } else if (i < 110592 + 49152) {
        int j = i - 110592;
        int t = j / 12288, rem = j - t * 12288;
        int h = rem >> 12, nm = rem & 4095;
        int n = nm >> 6, m = nm & 63;
        float v = -10000.f;
        if (n < 49 && m < 49) {
            int i1 = n / 7, j1 = n - i1 * 7, i2 = m / 7, j2 = m - i2 * 7;
            int rel = (i1 - i2 + 6) * 13 + (j1 - j2 + 6);
            int rep = ((t & 1) ? 31 : 0) + ((t & 2) ? 992 : 0);
            v = rpb[rel * 3 + h] + mask[rep * 2401 + n * 49 + m];
        }
        cmb[j] = v;
    }
}

// ---------------------------------------------------------------------------
// K1: fused LN1 + roll + window partition + QKV GEMM + attention.
// In-register softmax row-sum (no ones-row/MFMA normalization); vt = [32][72].
__global__ __launch_bounds__(192) void k_attnf(const float* __restrict__ x,
                                               const float* __restrict__ g1,
                                               const float* __restrict__ be1,
                                               const unsigned short* __restrict__ qkvwb,
                                               const float* __restrict__ qkvb,
                                               const float* __restrict__ cmb,
                                               unsigned short* __restrict__ aout) {
    __shared__ unsigned short smem[6912 + 3 * 5120];  // 44.5 KB
    unsigned short* xs = smem;  // [64][104] LN'd tokens (6656 <= 6912)

    unsigned win = blockIdx.x;
    unsigned b = win >> 10, widx = win & 1023u;
    unsigned wi = widx >> 5, wj = widx & 31u;
    int tid = threadIdx.x, wv = tid >> 6, lane = tid & 63;
    int half = lane >> 5, lch = lane & 31;

    // ---- phase 0: LN1 over the 49 tokens (with cyclic roll gather) ----
    for (int it = 0; it < 9; ++it) {
        int tok = it * 6 + wv * 2 + half;
        if (tok < 49) {
            unsigned i = (unsigned)tok / 7u, j = (unsigned)tok - i * 7u;
            unsigned sr = wi * 7 + i + 3; if (sr >= 224) sr -= 224;
            unsigned sc = wj * 7 + j + 3; if (sc >= 224) sc -= 224;
            const float* src = x + (size_t)(b * 50176u + sr * 224u + sc) * 96;
            float v0 = src[lch], v1 = src[lch + 32], v2 = src[lch + 64];
            float s = v0 + v1 + v2, q = v0 * v0 + v1 * v1 + v2 * v2;
#pragma unroll
            for (int off = 1; off < 32; off <<= 1) {
                s += __shfl_xor(s, off);
                q += __shfl_xor(q, off);
            }
            float mu = s * (1.f / 96.f);
            float rstd = rsqrtf(q * (1.f / 96.f) - mu * mu + 1e-5f);
            xs[tok * 104 + lch]      = f2bn((v0 - mu) * rstd * g1[lch] + be1[lch]);
            xs[tok * 104 + lch + 32] = f2bn((v1 - mu) * rstd * g1[lch + 32] + be1[lch + 32]);
            xs[tok * 104 + lch + 64] = f2bn((v2 - mu) * rstd * g1[lch + 64] + be1[lch + 64]);
        }
    }
    for (int t = tid; t < 15 * 96; t += 192)
        xs[(49 + t / 96) * 104 + (t % 96)] = 0;  // zero pad rows 49..63
    __syncthreads();

    // ---- phase 1: per-head QKV GEMM (swapped: A=weights, B=tokens) ----
    int h = wv;
    int rlo = lane & 15, g4 = lane >> 4;
    bfv8 a[4][3];
#pragma unroll
    for (int mt = 0; mt < 4; ++mt)
#pragma unroll
        for (int ks = 0; ks < 3; ++ks)
            a[mt][ks] = ldb8(xs + (mt * 16 + rlo) * 104 + ks * 32 + g4 * 8);
    __syncthreads();  // xs dead everywhere; per-head regions are private below

    unsigned short* vtH = smem + h * 2304;         // [32][72], rows d
    unsigned short* qH  = smem + 6912 + h * 5120;  // [64][40]
    unsigned short* kH  = qH + 2560;                // [64][40]
    unsigned short* pH  = qH;                       // P [64][72] overlays q|k

    const float SC = 0.17677669529663687f;
    int colbase[6] = {32 * h, 32 * h + 16, 96 + 32 * h, 96 + 32 * h + 16,
                      192 + 32 * h, 192 + 32 * h + 16};
#pragma unroll
    for (int grp = 0; grp < 2; ++grp) {
        bfv8 wS[3][3];
        f32x4 bS[3];
#pragma unroll
        for (int q3 = 0; q3 < 3; ++q3) {
            int c = colbase[grp * 3 + q3] + rlo;
            wS[q3][0] = ldb8(qkvwb + (size_t)c * 96 + g4 * 8);
            wS[q3][1] = ldb8(qkvwb + (size_t)c * 96 + 32 + g4 * 8);
            wS[q3][2] = ldb8(qkvwb + (size_t)c * 96 + 64 + g4 * 8);
            bS[q3] = *(const f32x4*)(qkvb + colbase[grp * 3 + q3] + g4 * 4);
        }
#pragma unroll
        for (int q3 = 0; q3 < 3; ++q3) {
            int nt = grp * 3 + q3;
#pragma unroll
            for (int mt = 0; mt < 4; ++mt) {
                f32x4 acc = {0.f, 0.f, 0.f, 0.f};
                acc = __builtin_amdgcn_mfma_f32_16x16x32_bf16(wS[q3][0], a[mt][0], acc, 0, 0, 0);
                acc = __builtin_amdgcn_mfma_f32_16x16x32_bf16(wS[q3][1], a[mt][1], acc, 0, 0, 0);
                acc = __builtin_amdgcn_mfma_f32_16x16x32_bf16(wS[q3][2], a[mt][2], acc, 0, 0, 0);
                int token = mt * 16 + rlo;
                if (nt < 2) {
                    f32x4 v = (acc + bS[q3]) * SC;
                    stb4(qH + token * 40 + nt * 16 + g4 * 4, v);
                } else if (nt < 4) {
                    f32x4 v = acc + bS[q3];
                    stb4(kH + token * 40 + (nt - 2) * 16 + g4 * 4, v);
                } else {
#pragma unroll
                    for (int r = 0; r < 4; ++r)  // V^T: 4 d-rows, same token col
                        vtH[((nt - 4) * 16 + g4 * 4 + r) * 72 + token] =
                            f2bn(acc[r] + bS[q3][r]);
                }
            }
        }
    }

    // ---- phase 2: attention (swapped QK: A=keys, B=queries) ----
    bfv8 qf[4], kf[4];
#pragma unroll
    for (int t = 0; t < 4; ++t) {
        qf[t] = ldb8(qH + (t * 16 + rlo) * 40 + g4 * 8);
        kf[t] = ldb8(kH + (t * 16 + rlo) * 40 + g4 * 8);
    }
    f32x4 s[4][4];  // lane: query=rlo, keys g4*4+r
#pragma unroll
    for (int mt = 0; mt < 4; ++mt)
#pragma unroll
        for (int nt = 0; nt < 4; ++nt) {
            f32x4 acc0 = {0.f, 0.f, 0.f, 0.f};
            s[mt][nt] = __builtin_amdgcn_mfma_f32_16x16x32_bf16(kf[nt], qf[mt], acc0, 0, 0, 0);
        }
    int type = ((wi == 31) ? 2 : 0) | ((wj == 31) ? 1 : 0);
    const float* crow = cmb + ((size_t)(type * 3 + h) << 12);
    // softmax: exp + in-register row-sum (lane holds 16 of 64 keys for its query)
#pragma unroll
    for (int mt = 0; mt < 4; ++mt) {
        int query = mt * 16 + rlo;
        const float* cr = crow + query * 64;
        float rsum = 0.f;
#pragma unroll
        for (int nt = 0; nt < 4; ++nt) {
            f32x4 cv = *(const f32x4*)(cr + nt * 16 + g4 * 4);
#pragma unroll
            for (int r = 0; r < 4; ++r) {
                float p = __expf(s[mt][nt][r] + cv[r]);
                s[mt][nt][r] = p;
                rsum += p;
            }
        }
        rsum += __shfl_xor(rsum, 16);
        rsum += __shfl_xor(rsum, 32);
        float inv = 1.f / rsum;
#pragma unroll
        for (int nt = 0; nt < 4; ++nt) {
            f32x4 v = s[mt][nt] * inv;
            stb4(pH + query * 72 + nt * 16 + g4 * 4, v);
        }
    }
    // V^T fragments as A (rows = d)
    bfv8 vf[2][2];
#pragma unroll
    for (int ks = 0; ks < 2; ++ks)
#pragma unroll
        for (int db = 0; db < 2; ++db)
            vf[ks][db] = ldb8(vtH + (db * 16 + rlo) * 72 + ks * 32 + g4 * 8);
#pragma unroll
    for (int mt = 0; mt < 4; ++mt) {
        bfv8 pa0 = ldb8(pH + (mt * 16 + rlo) * 72 + g4 * 8);
        bfv8 pa1 = ldb8(pH + (mt * 16 + rlo) * 72 + 32 + g4 * 8);
        int query = mt * 16 + rlo;
#pragma unroll
        for (int db = 0; db < 2; ++db) {
            f32x4 acc = {0.f, 0.f, 0.f, 0.f};
            acc = __builtin_amdgcn_mfma_f32_16x16x32_bf16(vf[0][db], pa0, acc, 0, 0, 0);
            acc = __builtin_amdgcn_mfma_f32_16x16x32_bf16(vf[1][db], pa1, acc, 0, 0, 0);
            if (query < 49)
                stb4(aout + ((size_t)win * 49 + query) * 96 + h * 32 + db * 16 + g4 * 4, acc);
        }
    }
}

// ---------------------------------------------------------------------------
// K2 v8: fused proj + residual + LN2 + MLP + residual.  128 threads = 2
// INDEPENDENT waves (zero barriers); wave-private LDS [32][136] (17.4 KB/block
// -> 8 blocks/CU under launch_bounds(128,4), VGPR cap 128 >= measured 84).
// fc1/fc2 pipelined in 3 chunks of 128 columns through the private m1 tile.
__global__ __launch_bounds__(128, 4) void k_pm(const unsigned short* __restrict__ aout,
                                               const unsigned short* __restrict__ projwb,
                                               const float* __restrict__ projb,
                                               const float* __restrict__ x,
                                               const float* __restrict__ g2,
                                               const float* __restrict__ be2,
                                               const unsigned short* __restrict__ w1b,
                                               const float* __restrict__ bias1,
                                               const unsigned short* __restrict__ w2b,
                                               const float* __restrict__ bias2,
                                               float* __restrict__ out) {
    __shared__ unsigned short smem[2 * 32 * 136];  // 17.4 KB -> 8 blocks/CU
    int lane = threadIdx.x & 63, wv = threadIdx.x >> 6;  // wv in {0,1}
    int rlo = lane & 15, g4 = lane >> 4;
    size_t tok0 = (size_t)blockIdx.x * 64;
    unsigned short* mw = smem + wv * 4352;  // wave-private [32][136]; xn overlays

    // 2 token tiles per wave
    bfv8 a0[2][3];
    int pix[2];
#pragma unroll
    for (int t = 0; t < 2; ++t) {
        int tt = 2 * wv + t;
        const unsigned short* p = aout + (tok0 + tt * 16 + rlo) * 96 + g4 * 8;
        a0[t][0] = ldb8(p); a0[t][1] = ldb8(p + 32); a0[t][2] = ldb8(p + 64);
        unsigned wt = (unsigned)(tok0 + tt * 16 + rlo);
        unsigned win = wt / 49u, n = wt - win * 49u;
        unsigned b = win >> 10, widx = win & 1023u;
        unsigned wi = widx >> 5, wj = widx & 31u;
        unsigned i = n / 7u, j = n - i * 7u;
        unsigned sr = wi * 7 + i + 3; if (sr >= 224) sr -= 224;
        unsigned sc = wj * 7 + j + 3; if (sc >= 224) sc -= 224;
        pix[t] = (int)(b * 50176u + sr * 224u + sc);
    }

    // ---- phase P: proj (swapped) + residual + LN2 stats; xv stays in regs ----
    f32x4 xv[2][6];
    float rs[2] = {0.f, 0.f}, rq[2] = {0.f, 0.f};
#pragma unroll
    for (int nt = 0; nt < 6; ++nt) {
        int c = nt * 16 + rlo;
        bfv8 b0 = ldb8(projwb + (size_t)c * 96 + g4 * 8);
        bfv8 b1 = ldb8(projwb + (size_t)c * 96 + 32 + g4 * 8);
        bfv8 b2 = ldb8(projwb + (size_t)c * 96 + 64 + g4 * 8);
        f32x4 bv = *(const f32x4*)(projb + nt * 16 + g4 * 4);
#pragma unroll
        for (int t = 0; t < 2; ++t) {
            f32x4 acc = {0.f, 0.f, 0.f, 0.f};
            acc = __builtin_amdgcn_mfma_f32_16x16x32_bf16(b0, a0[t][0], acc, 0, 0, 0);
            acc = __builtin_amdgcn_mfma_f32_16x16x32_bf16(b1, a0[t][1], acc, 0, 0, 0);
            acc = __builtin_amdgcn_mfma_f32_16x16x32_bf16(b2, a0[t][2], acc, 0, 0, 0);
            f32x4 xr = *(const f32x4*)(x + (size_t)pix[t] * 96 + nt * 16 + g4 * 4);
            f32x4 v = acc + bv + xr;
            xv[t][nt] = v;
            rs[t] += v[0] + v[1] + v[2] + v[3];
            rq[t] += v[0] * v[0] + v[1] * v[1] + v[2] * v[2] + v[3] * v[3];
        }
    }
#pragma unroll
    for (int t = 0; t < 2; ++t) {
        float s = rs[t], q = rq[t];
        s += __shfl_xor(s, 16); q += __shfl_xor(q, 16);
        s += __shfl_xor(s, 32); q += __shfl_xor(q, 32);
        float mu = s * (1.f / 96.f);
        float rstd = rsqrtf(q * (1.f / 96.f) - mu * mu + 1e-5f);
#pragma unroll
        for (int nt = 0; nt < 6; ++nt) {
            f32x4 gg = *(const f32x4*)(g2 + nt * 16 + g4 * 4);
            f32x4 bb = *(const f32x4*)(be2 + nt * 16 + g4 * 4);
            f32x4 v;
#pragma unroll
            for (int r = 0; r < 4; ++r) v[r] = (xv[t][nt][r] - mu) * rstd * gg[r] + bb[r];
            stb4(mw + (t * 16 + rlo) * 136 + nt * 16 + g4 * 4, v);  // xn (overlays m1)
        }
    }
    // fc1 B-frags for the wave's 32 rows (from private xn; in-wave lgkmcnt order)
    bfv8 af[2][3];
#pragma unroll
    for (int mt = 0; mt < 2; ++mt)
#pragma unroll
        for (int ks = 0; ks < 3; ++ks)
            af[mt][ks] = ldb8(mw + (mt * 16 + rlo) * 136 + ks * 32 + g4 * 8);

    f32x4 acc2[2][6];
#pragma unroll
    for (int t = 0; t < 2; ++t)
#pragma unroll
        for (int nt = 0; nt < 6; ++nt) acc2[t][nt] = {0.f, 0.f, 0.f, 0.f};

#pragma unroll
    for (int ch = 0; ch < 3; ++ch) {
        // ---- fc1 chunk: 8 col-tiles (128 cols) -> GELU -> private m1 ----
#pragma unroll
        for (int ct = 0; ct < 8; ++ct) {
            int cb = ch * 128 + ct * 16;
            int c = cb + rlo;
            bfv8 b0 = ldb8(w1b + (size_t)c * 96 + g4 * 8);
            bfv8 b1 = ldb8(w1b + (size_t)c * 96 + 32 + g4 * 8);
            bfv8 b2 = ldb8(w1b + (size_t)c * 96 + 64 + g4 * 8);
            f32x4 bv = *(const f32x4*)(bias1 + cb + g4 * 4);
#pragma unroll
            for (int mt = 0; mt < 2; ++mt) {
                f32x4 acc = {0.f, 0.f, 0.f, 0.f};
                acc = __builtin_amdgcn_mfma_f32_16x16x32_bf16(b0, af[mt][0], acc, 0, 0, 0);
                acc = __builtin_amdgcn_mfma_f32_16x16x32_bf16(b1, af[mt][1], acc, 0, 0, 0);
                acc = __builtin_amdgcn_mfma_f32_16x16x32_bf16(b2, af[mt][2], acc, 0, 0, 0);
                f32x4 g;
#pragma unroll
                for (int r = 0; r < 4; ++r) {
                    float v = acc[r] + bv[r];
                    float z = 1.5957691216057308f * (v + 0.044715f * v * v * v);
                    g[r] = v / (1.f + __expf(-z));
                }
                stb4(mw + (mt * 16 + rlo) * 136 + ct * 16 + g4 * 4, g);  // m1 chunk
            }
        }
        // ---- fc2 chunk: 4 K-slices over the private m1 chunk ----
#pragma unroll
        for (int ks = 0; ks < 4; ++ks) {
            bfv8 am0 = ldb8(mw + (0 * 16 + rlo) * 136 + ks * 32 + g4 * 8);
            bfv8 am1 = ldb8(mw + (1 * 16 + rlo) * 136 + ks * 32 + g4 * 8);
#pragma unroll
            for (int nt = 0; nt < 6; ++nt) {
                bfv8 bw = ldb8(w2b + (size_t)(nt * 16 + rlo) * 384 + ch * 128 + ks * 32 + g4 * 8);
                acc2[0][nt] = __builtin_amdgcn_mfma_f32_16x16x32_bf16(bw, am0, acc2[0][nt], 0, 0, 0);
                acc2[1][nt] = __builtin_amdgcn_mfma_f32_16x16x32_bf16(bw, am1, acc2[1][nt], 0, 0, 0);
            }
        }
    }

    // ---- epilogue: out = fc2 + bias2 + x1 (from registers) ----
#pragma unroll
    for (int t = 0; t < 2; ++t)
#pragma unroll
        for (int nt = 0; nt < 6; ++nt) {
            f32x4 bv = *(const f32x4*)(bias2 + nt * 16 + g4 * 4);
            f32x4 ov = acc2[t][nt] + bv + xv[t][nt];
            *(f32x4*)(out + (size_t)pix[t] * 96 + nt * 16 + g4 * 4) = ov;
        }
}

// ---------------------------------------------------------------------------
extern "C" void kernel_launch(void* const* d_in, const int* in_sizes, int n_in,
                              void* d_out, int out_size, void* d_ws, size_t ws_size,
                              hipStream_t stream) {
    const float* x     = (const float*)d_in[0];
    const float* mask  = (const float*)d_in[1];
    const float* n1g   = (const float*)d_in[2];
    const float* n1b   = (const float*)d_in[3];
    const float* qkvw  = (const float*)d_in[4];
    const float* qkvb  = (const float*)d_in[5];
    const float* rpb   = (const float*)d_in[6];
    const float* projw = (const float*)d_in[7];
    const float* projb = (const float*)d_in[8];
    const float* n2g   = (const float*)d_in[9];
    const float* n2b   = (const float*)d_in[10];
    const float* fc1w  = (const float*)d_in[11];
    const float* fc1b  = (const float*)d_in[12];
    const float* fc2w  = (const float*)d_in[13];
    const float* fc2b  = (const float*)d_in[14];

    // ws: aout(bf16) [0,77.07M) ; wb(bf16,221KB) @77070336 ; cmb(fp32,192KB) @77291520
    if (ws_size < 77488128ULL) return;
    char* ws = (char*)d_ws;
    unsigned short* aout = (unsigned short*)ws;
    unsigned short* wb   = (unsigned short*)(ws + 77070336);
    float*          cmb  = (float*)(ws + 77291520);
    float*          out  = (float*)d_out;

    unsigned short* qkvwb  = wb;          // 27648
    unsigned short* projwb = wb + 27648;  // 9216
    unsigned short* fc1wb  = wb + 36864;  // 36864
    unsigned short* fc2wb  = wb + 73728;  // 36864

    k_prep<<<624, 256, 0, stream>>>(qkvw, projw, fc1w, fc2w, rpb, mask, wb, cmb);
    k_attnf<<<8192, 192, 0, stream>>>(x, n1g, n1b, qkvwb, qkvb, cmb, aout);
    k_pm<<<T / 64, 128, 0, stream>>>(aout, projwb, projb, x, n2g, n2b,
                                     fc1wb, fc1b, fc2wb, fc2b, out);
}

// Round 19
// 462.961 us; speedup vs baseline: 1.1464x; 1.1464x over previous
//
#include <hip/hip_runtime.h>
#include <hip/hip_bf16.h>
#include <stdint.h>

typedef __attribute__((ext_vector_type(4))) float f32x4;
typedef __bf16 bfv8 __attribute__((ext_vector_type(8)));
typedef unsigned short u16x8 __attribute__((ext_vector_type(8)));
typedef unsigned short u16x4 __attribute__((ext_vector_type(4)));

#define DEV static __device__ __forceinline__

DEV float b2f(unsigned short h) {
    unsigned u = ((unsigned)h) << 16;
    return __builtin_bit_cast(float, u);
}
DEV unsigned short f2b(float f) {  // cold paths only
    unsigned u = __builtin_bit_cast(unsigned, f);
    u += 0x7fffu + ((u >> 16) & 1u);
    return (unsigned short)(u >> 16);
}
DEV unsigned short f2bn(float f) {
    return __builtin_bit_cast(unsigned short, (__bf16)f);
}
DEV bfv8 ldb8(const unsigned short* p) {
    return __builtin_bit_cast(bfv8, *(const u16x8*)p);
}
DEV void stb4(unsigned short* p, f32x4 v) {
    u16x4 o;
    o[0] = f2bn(v[0]); o[1] = f2bn(v[1]); o[2] = f2bn(v[2]); o[3] = f2bn(v[3]);
    *(u16x4*)p = o;
}

// B=8, H=W=224, C=96, WS=7, SS=3, NH=3, HD=32, N=49, nW=1024, B_=8192
static constexpr int T = 401408;  // B_ * N tokens

// ---------------------------------------------------------------------------
// K0: one-shot prep: fp32->bf16 weights + combined rel-pos-bias/shift-mask table.
__global__ __launch_bounds__(256) void k_prep(const float* __restrict__ qkvw,
                                              const float* __restrict__ projw,
                                              const float* __restrict__ w1,
                                              const float* __restrict__ w2,
                                              const float* __restrict__ rpb,
                                              const float* __restrict__ mask,
                                              unsigned short* __restrict__ wb,
                                              float* __restrict__ cmb) {
    int i = blockIdx.x * 256 + threadIdx.x;
    if (i < 110592) {
        float v;
        if (i < 27648) v = qkvw[i];
        else if (i < 36864) v = projw[i - 27648];
        else if (i < 73728) v = w1[i - 36864];
        else v = w2[i - 73728];
        wb[i] = f2b(v);
    } else if (i < 110592 + 49152) {
        int j = i - 110592;
        int t = j / 12288, rem = j - t * 12288;
        int h = rem >> 12, nm = rem & 4095;
        int n = nm >> 6, m = nm & 63;
        float v = -10000.f;
        if (n < 49 && m < 49) {
            int i1 = n / 7, j1 = n - i1 * 7, i2 = m / 7, j2 = m - i2 * 7;
            int rel = (i1 - i2 + 6) * 13 + (j1 - j2 + 6);
            int rep = ((t & 1) ? 31 : 0) + ((t & 2) ? 992 : 0);
            v = rpb[rel * 3 + h] + mask[rep * 2401 + n * 49 + m];
        }
        cmb[j] = v;
    }
}

// ---------------------------------------------------------------------------
// K1: fused LN1 + roll + window partition + QKV GEMM + attention (R17 form).
__global__ __launch_bounds__(192) void k_attnf(const float* __restrict__ x,
                                               const float* __restrict__ g1,
                                               const float* __restrict__ be1,
                                               const unsigned short* __restrict__ qkvwb,
                                               const float* __restrict__ qkvb,
                                               const float* __restrict__ cmb,
                                               unsigned short* __restrict__ aout) {
    __shared__ unsigned short smem[10368 + 3 * 5120];
    unsigned short* xs = smem;  // [64][104] LN'd tokens, dead after A-frag load

    unsigned win = blockIdx.x;
    unsigned b = win >> 10, widx = win & 1023u;
    unsigned wi = widx >> 5, wj = widx & 31u;
    int tid = threadIdx.x, wv = tid >> 6, lane = tid & 63;
    int half = lane >> 5, lch = lane & 31;

    // ---- phase 0: LN1 over the 49 tokens (with cyclic roll gather) ----
    for (int it = 0; it < 9; ++it) {
        int tok = it * 6 + wv * 2 + half;
        if (tok < 49) {
            unsigned i = (unsigned)tok / 7u, j = (unsigned)tok - i * 7u;
            unsigned sr = wi * 7 + i + 3; if (sr >= 224) sr -= 224;
            unsigned sc = wj * 7 + j + 3; if (sc >= 224) sc -= 224;
            const float* src = x + (size_t)(b * 50176u + sr * 224u + sc) * 96;
            float v0 = src[lch], v1 = src[lch + 32], v2 = src[lch + 64];
            float s = v0 + v1 + v2, q = v0 * v0 + v1 * v1 + v2 * v2;
#pragma unroll
            for (int off = 1; off < 32; off <<= 1) {
                s += __shfl_xor(s, off);
                q += __shfl_xor(q, off);
            }
            float mu = s * (1.f / 96.f);
            float rstd = rsqrtf(q * (1.f / 96.f) - mu * mu + 1e-5f);
            xs[tok * 104 + lch]      = f2bn((v0 - mu) * rstd * g1[lch] + be1[lch]);
            xs[tok * 104 + lch + 32] = f2bn((v1 - mu) * rstd * g1[lch + 32] + be1[lch + 32]);
            xs[tok * 104 + lch + 64] = f2bn((v2 - mu) * rstd * g1[lch + 64] + be1[lch + 64]);
        }
    }
    for (int t = tid; t < 15 * 96; t += 192)
        xs[(49 + t / 96) * 104 + (t % 96)] = 0;  // zero pad rows 49..63
    __syncthreads();

    // ---- phase 1: per-head QKV GEMM (swapped: A=weights, B=tokens) ----
    int h = wv;
    int rlo = lane & 15, g4 = lane >> 4;
    bfv8 a[4][3];
#pragma unroll
    for (int mt = 0; mt < 4; ++mt)
#pragma unroll
        for (int ks = 0; ks < 3; ++ks)
            a[mt][ks] = ldb8(xs + (mt * 16 + rlo) * 104 + ks * 32 + g4 * 8);
    __syncthreads();  // xs dead everywhere; per-head regions are private below

    unsigned short* vtH = smem + h * 3456;          // [48][72], rows d; row32=ones
    unsigned short* qH  = smem + 10368 + h * 5120;  // [64][40]
    unsigned short* kH  = qH + 2560;                // [64][40]
    unsigned short* pH  = qH;                       // P [64][72] overlays q|k

    const float SC = 0.17677669529663687f;
    int colbase[6] = {32 * h, 32 * h + 16, 96 + 32 * h, 96 + 32 * h + 16,
                      192 + 32 * h, 192 + 32 * h + 16};
#pragma unroll
    for (int grp = 0; grp < 2; ++grp) {
        bfv8 wS[3][3];
        f32x4 bS[3];
#pragma unroll
        for (int q3 = 0; q3 < 3; ++q3) {
            int c = colbase[grp * 3 + q3] + rlo;
            wS[q3][0] = ldb8(qkvwb + (size_t)c * 96 + g4 * 8);
            wS[q3][1] = ldb8(qkvwb + (size_t)c * 96 + 32 + g4 * 8);
            wS[q3][2] = ldb8(qkvwb + (size_t)c * 96 + 64 + g4 * 8);
            bS[q3] = *(const f32x4*)(qkvb + colbase[grp * 3 + q3] + g4 * 4);
        }
#pragma unroll
        for (int q3 = 0; q3 < 3; ++q3) {
            int nt = grp * 3 + q3;
#pragma unroll
            for (int mt = 0; mt < 4; ++mt) {
                f32x4 acc = {0.f, 0.f, 0.f, 0.f};
                acc = __builtin_amdgcn_mfma_f32_16x16x32_bf16(wS[q3][0], a[mt][0], acc, 0, 0, 0);
                acc = __builtin_amdgcn_mfma_f32_16x16x32_bf16(wS[q3][1], a[mt][1], acc, 0, 0, 0);
                acc = __builtin_amdgcn_mfma_f32_16x16x32_bf16(wS[q3][2], a[mt][2], acc, 0, 0, 0);
                int token = mt * 16 + rlo;
                if (nt < 2) {
                    f32x4 v = (acc + bS[q3]) * SC;
                    stb4(qH + token * 40 + nt * 16 + g4 * 4, v);
                } else if (nt < 4) {
                    f32x4 v = acc + bS[q3];
                    stb4(kH + token * 40 + (nt - 2) * 16 + g4 * 4, v);
                } else {
#pragma unroll
                    for (int r = 0; r < 4; ++r)  // V^T: 4 d-rows, same token col
                        vtH[((nt - 4) * 16 + g4 * 4 + r) * 72 + token] =
                            f2bn(acc[r] + bS[q3][r]);
                }
            }
        }
    }
    vtH[32 * 72 + lane] = 0x3F80;  // ones row for row-sum via MFMA

    // ---- phase 2: attention (swapped QK: A=keys, B=queries) ----
    bfv8 qf[4], kf[4];
#pragma unroll
    for (int t = 0; t < 4; ++t) {
        qf[t] = ldb8(qH + (t * 16 + rlo) * 40 + g4 * 8);
        kf[t] = ldb8(kH + (t * 16 + rlo) * 40 + g4 * 8);
    }
    f32x4 s[4][4];  // lane: query=rlo, keys g4*4+r
#pragma unroll
    for (int mt = 0; mt < 4; ++mt)
#pragma unroll
        for (int nt = 0; nt < 4; ++nt) {
            f32x4 acc0 = {0.f, 0.f, 0.f, 0.f};
            s[mt][nt] = __builtin_amdgcn_mfma_f32_16x16x32_bf16(kf[nt], qf[mt], acc0, 0, 0, 0);
        }
    int type = ((wi == 31) ? 2 : 0) | ((wj == 31) ? 1 : 0);
    const float* crow = cmb + ((size_t)(type * 3 + h) << 12);
#pragma unroll
    for (int mt = 0; mt < 4; ++mt) {
        int query = mt * 16 + rlo;
        const float* cr = crow + query * 64;
#pragma unroll
        for (int nt = 0; nt < 4; ++nt) {
            f32x4 cv = *(const f32x4*)(cr + nt * 16 + g4 * 4);
            f32x4 p;
#pragma unroll
            for (int r = 0; r < 4; ++r) p[r] = __expf(s[mt][nt][r] + cv[r]);
            stb4(pH + query * 72 + nt * 16 + g4 * 4, p);
        }
    }
    // V^T fragments as A (rows = d); db=2 is the ones/sum tile
    bfv8 vf[2][3];
#pragma unroll
    for (int ks = 0; ks < 2; ++ks)
#pragma unroll
        for (int db = 0; db < 3; ++db)
            vf[ks][db] = ldb8(vtH + (db * 16 + rlo) * 72 + ks * 32 + g4 * 8);
#pragma unroll
    for (int mt = 0; mt < 4; ++mt) {
        bfv8 pa0 = ldb8(pH + (mt * 16 + rlo) * 72 + g4 * 8);
        bfv8 pa1 = ldb8(pH + (mt * 16 + rlo) * 72 + 32 + g4 * 8);
        f32x4 acc[3];
#pragma unroll
        for (int db = 0; db < 3; ++db) {
            acc[db] = {0.f, 0.f, 0.f, 0.f};
            acc[db] = __builtin_amdgcn_mfma_f32_16x16x32_bf16(vf[0][db], pa0, acc[db], 0, 0, 0);
            acc[db] = __builtin_amdgcn_mfma_f32_16x16x32_bf16(vf[1][db], pa1, acc[db], 0, 0, 0);
        }
        float inv = 1.f / __shfl(acc[2][0], rlo);
        int query = mt * 16 + rlo;
        if (query < 49) {
            unsigned short* ob = aout + ((size_t)win * 49 + query) * 96 + h * 32;
#pragma unroll
            for (int db = 0; db < 2; ++db) {
                f32x4 v = acc[db] * inv;
                stb4(ob + db * 16 + g4 * 4, v);
            }
        }
    }
}

// ---------------------------------------------------------------------------
// K2 v9: fused proj + residual + LN2 + MLP + residual.  128 threads = 2
// INDEPENDENT waves (zero barriers); wave-private LDS [32][140] (stride 70 dw
// = 6 mod 32, conflict-free; 17.9 KB/block -> 8 blocks/CU).  launch_bounds
// (128,3) keeps the R17-proven VGPR=84 allocation (no spill).  fc1/fc2 in 3
// chunks of 128 cols through the private m1 tile.
__global__ __launch_bounds__(128, 3) void k_pm(const unsigned short* __restrict__ aout,
                                               const unsigned short* __restrict__ projwb,
                                               const float* __restrict__ projb,
                                               const float* __restrict__ x,
                                               const float* __restrict__ g2,
                                               const float* __restrict__ be2,
                                               const unsigned short* __restrict__ w1b,
                                               const float* __restrict__ bias1,
                                               const unsigned short* __restrict__ w2b,
                                               const float* __restrict__ bias2,
                                               float* __restrict__ out) {
    __shared__ unsigned short smem[2 * 32 * 140];  // 17.9 KB -> 8 blocks/CU
    int lane = threadIdx.x & 63, wv = threadIdx.x >> 6;  // wv in {0,1}
    int rlo = lane & 15, g4 = lane >> 4;
    size_t tok0 = (size_t)blockIdx.x * 64;
    unsigned short* mw = smem + wv * 4480;  // wave-private [32][140]; xn overlays

    // 2 token tiles per wave
    bfv8 a0[2][3];
    int pix[2];
#pragma unroll
    for (int t = 0; t < 2; ++t) {
        int tt = 2 * wv + t;
        const unsigned short* p = aout + (tok0 + tt * 16 + rlo) * 96 + g4 * 8;
        a0[t][0] = ldb8(p); a0[t][1] = ldb8(p + 32); a0[t][2] = ldb8(p + 64);
        unsigned wt = (unsigned)(tok0 + tt * 16 + rlo);
        unsigned win = wt / 49u, n = wt - win * 49u;
        unsigned b = win >> 10, widx = win & 1023u;
        unsigned wi = widx >> 5, wj = widx & 31u;
        unsigned i = n / 7u, j = n - i * 7u;
        unsigned sr = wi * 7 + i + 3; if (sr >= 224) sr -= 224;
        unsigned sc = wj * 7 + j + 3; if (sc >= 224) sc -= 224;
        pix[t] = (int)(b * 50176u + sr * 224u + sc);
    }

    // ---- phase P: proj (swapped) + residual + LN2 stats; xv stays in regs ----
    f32x4 xv[2][6];
    float rs[2] = {0.f, 0.f}, rq[2] = {0.f, 0.f};
#pragma unroll
    for (int nt = 0; nt < 6; ++nt) {
        int c = nt * 16 + rlo;
        bfv8 b0 = ldb8(projwb + (size_t)c * 96 + g4 * 8);
        bfv8 b1 = ldb8(projwb + (size_t)c * 96 + 32 + g4 * 8);
        bfv8 b2 = ldb8(projwb + (size_t)c * 96 + 64 + g4 * 8);
        f32x4 bv = *(const f32x4*)(projb + nt * 16 + g4 * 4);
#pragma unroll
        for (int t = 0; t < 2; ++t) {
            f32x4 acc = {0.f, 0.f, 0.f, 0.f};
            acc = __builtin_amdgcn_mfma_f32_16x16x32_bf16(b0, a0[t][0], acc, 0, 0, 0);
            acc = __builtin_amdgcn_mfma_f32_16x16x32_bf16(b1, a0[t][1], acc, 0, 0, 0);
            acc = __builtin_amdgcn_mfma_f32_16x16x32_bf16(b2, a0[t][2], acc, 0, 0, 0);
            f32x4 xr = *(const f32x4*)(x + (size_t)pix[t] * 96 + nt * 16 + g4 * 4);
            f32x4 v = acc + bv + xr;
            xv[t][nt] = v;
            rs[t] += v[0] + v[1] + v[2] + v[3];
            rq[t] += v[0] * v[0] + v[1] * v[1] + v[2] * v[2] + v[3] * v[3];
        }
    }
#pragma unroll
    for (int t = 0; t < 2; ++t) {
        float s = rs[t], q = rq[t];
        s += __shfl_xor(s, 16); q += __shfl_xor(q, 16);
        s += __shfl_xor(s, 32); q += __shfl_xor(q, 32);
        float mu = s * (1.f / 96.f);
        float rstd = rsqrtf(q * (1.f / 96.f) - mu * mu + 1e-5f);
#pragma unroll
        for (int nt = 0; nt < 6; ++nt) {
            f32x4 gg = *(const f32x4*)(g2 + nt * 16 + g4 * 4);
            f32x4 bb = *(const f32x4*)(be2 + nt * 16 + g4 * 4);
            f32x4 v;
#pragma unroll
            for (int r = 0; r < 4; ++r) v[r] = (xv[t][nt][r] - mu) * rstd * gg[r] + bb[r];
            stb4(mw + (t * 16 + rlo) * 140 + nt * 16 + g4 * 4, v);  // xn (overlays m1)
        }
    }
    // fc1 B-frags for the wave's 32 rows (from private xn; in-wave lgkmcnt order)
    bfv8 af[2][3];
#pragma unroll
    for (int mt = 0; mt < 2; ++mt)
#pragma unroll
        for (int ks = 0; ks < 3; ++ks)
            af[mt][ks] = ldb8(mw + (mt * 16 + rlo) * 140 + ks * 32 + g4 * 8);

    f32x4 acc2[2][6];
#pragma unroll
    for (int t = 0; t < 2; ++t)
#pragma unroll
        for (int nt = 0; nt < 6; ++nt) acc2[t][nt] = {0.f, 0.f, 0.f, 0.f};

#pragma unroll
    for (int ch = 0; ch < 3; ++ch) {
        // ---- fc1 chunk: 8 col-tiles (128 cols) -> GELU -> private m1 ----
#pragma unroll
        for (int ct = 0; ct < 8; ++ct) {
            int cb = ch * 128 + ct * 16;
            int c = cb + rlo;
            bfv8 b0 = ldb8(w1b + (size_t)c * 96 + g4 * 8);
            bfv8 b1 = ldb8(w1b + (size_t)c * 96 + 32 + g4 * 8);
            bfv8 b2 = ldb8(w1b + (size_t)c * 96 + 64 + g4 * 8);
            f32x4 bv = *(const f32x4*)(bias1 + cb + g4 * 4);
#pragma unroll
            for (int mt = 0; mt < 2; ++mt) {
                f32x4 acc = {0.f, 0.f, 0.f, 0.f};
                acc = __builtin_amdgcn_mfma_f32_16x16x32_bf16(b0, af[mt][0], acc, 0, 0, 0);
                acc = __builtin_amdgcn_mfma_f32_16x16x32_bf16(b1, af[mt][1], acc, 0, 0, 0);
                acc = __builtin_amdgcn_mfma_f32_16x16x32_bf16(b2, af[mt][2], acc, 0, 0, 0);
                f32x4 g;
#pragma unroll
                for (int r = 0; r < 4; ++r) {
                    float v = acc[r] + bv[r];
                    float z = 1.5957691216057308f * (v + 0.044715f * v * v * v);
                    g[r] = v / (1.f + __expf(-z));
                }
                stb4(mw + (mt * 16 + rlo) * 140 + ct * 16 + g4 * 4, g);  // m1 chunk
            }
        }
        // ---- fc2 chunk: 4 K-slices over the private m1 chunk ----
#pragma unroll
        for (int ks = 0; ks < 4; ++ks) {
            bfv8 am0 = ldb8(mw + (0 * 16 + rlo) * 140 + ks * 32 + g4 * 8);
            bfv8 am1 = ldb8(mw + (1 * 16 + rlo) * 140 + ks * 32 + g4 * 8);
#pragma unroll
            for (int nt = 0; nt < 6; ++nt) {
                bfv8 bw = ldb8(w2b + (size_t)(nt * 16 + rlo) * 384 + ch * 128 + ks * 32 + g4 * 8);
                acc2[0][nt] = __builtin_amdgcn_mfma_f32_16x16x32_bf16(bw, am0, acc2[0][nt], 0, 0, 0);
                acc2[1][nt] = __builtin_amdgcn_mfma_f32_16x16x32_bf16(bw, am1, acc2[1][nt], 0, 0, 0);
            }
        }
    }

    // ---- epilogue: out = fc2 + bias2 + x1 (from registers) ----
#pragma unroll
    for (int t = 0; t < 2; ++t)
#pragma unroll
        for (int nt = 0; nt < 6; ++nt) {
            f32x4 bv = *(const f32x4*)(bias2 + nt * 16 + g4 * 4);
            f32x4 ov = acc2[t][nt] + bv + xv[t][nt];
            *(f32x4*)(out + (size_t)pix[t] * 96 + nt * 16 + g4 * 4) = ov;
        }
}

// ---------------------------------------------------------------------------
extern "C" void kernel_launch(void* const* d_in, const int* in_sizes, int n_in,
                              void* d_out, int out_size, void* d_ws, size_t ws_size,
                              hipStream_t stream) {
    const float* x     = (const float*)d_in[0];
    const float* mask  = (const float*)d_in[1];
    const float* n1g   = (const float*)d_in[2];
    const float* n1b   = (const float*)d_in[3];
    const float* qkvw  = (const float*)d_in[4];
    const float* qkvb  = (const float*)d_in[5];
    const float* rpb   = (const float*)d_in[6];
    const float* projw = (const float*)d_in[7];
    const float* projb = (const float*)d_in[8];
    const float* n2g   = (const float*)d_in[9];
    const float* n2b   = (const float*)d_in[10];
    const float* fc1w  = (const float*)d_in[11];
    const float* fc1b  = (const float*)d_in[12];
    const float* fc2w  = (const float*)d_in[13];
    const float* fc2b  = (const float*)d_in[14];

    // ws: aout(bf16) [0,77.07M) ; wb(bf16,221KB) @77070336 ; cmb(fp32,192KB) @77291520
    if (ws_size < 77488128ULL) return;
    char* ws = (char*)d_ws;
    unsigned short* aout = (unsigned short*)ws;
    unsigned short* wb   = (unsigned short*)(ws + 77070336);
    float*          cmb  = (float*)(ws + 77291520);
    float*          out  = (float*)d_out;

    unsigned short* qkvwb  = wb;          // 27648
    unsigned short* projwb = wb + 27648;  // 9216
    unsigned short* fc1wb  = wb + 36864;  // 36864
    unsigned short* fc2wb  = wb + 73728;  // 36864

    k_prep<<<624, 256, 0, stream>>>(qkvw, projw, fc1w, fc2w, rpb, mask, wb, cmb);
    k_attnf<<<8192, 192, 0, stream>>>(x, n1g, n1b, qkvwb, qkvb, cmb, aout);
    k_pm<<<T / 64, 128, 0, stream>>>(aout, projwb, projb, x, n2g, n2b,
                                     fc1wb, fc1b, fc2wb, fc2b, out);
}

// Round 20
// 452.991 us; speedup vs baseline: 1.1716x; 1.0220x over previous
//
#include <hip/hip_runtime.h>
#include <hip/hip_bf16.h>
#include <stdint.h>

typedef __attribute__((ext_vector_type(4))) float f32x4;
typedef __bf16 bfv8 __attribute__((ext_vector_type(8)));
typedef unsigned short u16x8 __attribute__((ext_vector_type(8)));
typedef unsigned short u16x4 __attribute__((ext_vector_type(4)));

#define DEV static __device__ __forceinline__

DEV float b2f(unsigned short h) {
    unsigned u = ((unsigned)h) << 16;
    return __builtin_bit_cast(float, u);
}
DEV unsigned short f2b(float f) {  // cold paths only
    unsigned u = __builtin_bit_cast(unsigned, f);
    u += 0x7fffu + ((u >> 16) & 1u);
    return (unsigned short)(u >> 16);
}
DEV unsigned short f2bn(float f) {
    return __builtin_bit_cast(unsigned short, (__bf16)f);
}
DEV bfv8 ldb8(const unsigned short* p) {
    return __builtin_bit_cast(bfv8, *(const u16x8*)p);
}
DEV void stb4(unsigned short* p, f32x4 v) {
    u16x4 o;
    o[0] = f2bn(v[0]); o[1] = f2bn(v[1]); o[2] = f2bn(v[2]); o[3] = f2bn(v[3]);
    *(u16x4*)p = o;
}

// B=8, H=W=224, C=96, WS=7, SS=3, NH=3, HD=32, N=49, nW=1024, B_=8192
static constexpr int T = 401408;  // B_ * N tokens

// ---------------------------------------------------------------------------
// K0: one-shot prep: fp32->bf16 weights + combined rel-pos-bias/shift-mask table.
__global__ __launch_bounds__(256) void k_prep(const float* __restrict__ qkvw,
                                              const float* __restrict__ projw,
                                              const float* __restrict__ w1,
                                              const float* __restrict__ w2,
                                              const float* __restrict__ rpb,
                                              const float* __restrict__ mask,
                                              unsigned short* __restrict__ wb,
                                              float* __restrict__ cmb) {
    int i = blockIdx.x * 256 + threadIdx.x;
    if (i < 110592) {
        float v;
        if (i < 27648) v = qkvw[i];
        else if (i < 36864) v = projw[i - 27648];
        else if (i < 73728) v = w1[i - 36864];
        else v = w2[i - 73728];
        wb[i] = f2b(v);
    } else if (i < 110592 + 49152) {
        int j = i - 110592;
        int t = j / 12288, rem = j - t * 12288;
        int h = rem >> 12, nm = rem & 4095;
        int n = nm >> 6, m = nm & 63;
        float v = -10000.f;
        if (n < 49 && m < 49) {
            int i1 = n / 7, j1 = n - i1 * 7, i2 = m / 7, j2 = m - i2 * 7;
            int rel = (i1 - i2 + 6) * 13 + (j1 - j2 + 6);
            int rep = ((t & 1) ? 31 : 0) + ((t & 2) ? 992 : 0);
            v = rpb[rel * 3 + h] + mask[rep * 2401 + n * 49 + m];
        }
        cmb[j] = v;
    }
}

// ---------------------------------------------------------------------------
// K1: fused LN1 + roll + window partition + QKV GEMM + attention (R12/R17 form).
__global__ __launch_bounds__(192) void k_attnf(const float* __restrict__ x,
                                               const float* __restrict__ g1,
                                               const float* __restrict__ be1,
                                               const unsigned short* __restrict__ qkvwb,
                                               const float* __restrict__ qkvb,
                                               const float* __restrict__ cmb,
                                               unsigned short* __restrict__ aout) {
    __shared__ unsigned short smem[10368 + 3 * 5120];
    unsigned short* xs = smem;  // [64][104] LN'd tokens, dead after A-frag load

    unsigned win = blockIdx.x;
    unsigned b = win >> 10, widx = win & 1023u;
    unsigned wi = widx >> 5, wj = widx & 31u;
    int tid = threadIdx.x, wv = tid >> 6, lane = tid & 63;
    int half = lane >> 5, lch = lane & 31;

    // ---- phase 0: LN1 over the 49 tokens (with cyclic roll gather) ----
    for (int it = 0; it < 9; ++it) {
        int tok = it * 6 + wv * 2 + half;
        if (tok < 49) {
            unsigned i = (unsigned)tok / 7u, j = (unsigned)tok - i * 7u;
            unsigned sr = wi * 7 + i + 3; if (sr >= 224) sr -= 224;
            unsigned sc = wj * 7 + j + 3; if (sc >= 224) sc -= 224;
            const float* src = x + (size_t)(b * 50176u + sr * 224u + sc) * 96;
            float v0 = src[lch], v1 = src[lch + 32], v2 = src[lch + 64];
            float s = v0 + v1 + v2, q = v0 * v0 + v1 * v1 + v2 * v2;
#pragma unroll
            for (int off = 1; off < 32; off <<= 1) {
                s += __shfl_xor(s, off);
                q += __shfl_xor(q, off);
            }
            float mu = s * (1.f / 96.f);
            float rstd = rsqrtf(q * (1.f / 96.f) - mu * mu + 1e-5f);
            xs[tok * 104 + lch]      = f2bn((v0 - mu) * rstd * g1[lch] + be1[lch]);
            xs[tok * 104 + lch + 32] = f2bn((v1 - mu) * rstd * g1[lch + 32] + be1[lch + 32]);
            xs[tok * 104 + lch + 64] = f2bn((v2 - mu) * rstd * g1[lch + 64] + be1[lch + 64]);
        }
    }
    for (int t = tid; t < 15 * 96; t += 192)
        xs[(49 + t / 96) * 104 + (t % 96)] = 0;  // zero pad rows 49..63
    __syncthreads();

    // ---- phase 1: per-head QKV GEMM (swapped: A=weights, B=tokens) ----
    int h = wv;
    int rlo = lane & 15, g4 = lane >> 4;
    bfv8 a[4][3];
#pragma unroll
    for (int mt = 0; mt < 4; ++mt)
#pragma unroll
        for (int ks = 0; ks < 3; ++ks)
            a[mt][ks] = ldb8(xs + (mt * 16 + rlo) * 104 + ks * 32 + g4 * 8);
    __syncthreads();  // xs dead everywhere; per-head regions are private below

    unsigned short* vtH = smem + h * 3456;          // [48][72], rows d; row32=ones
    unsigned short* qH  = smem + 10368 + h * 5120;  // [64][40]
    unsigned short* kH  = qH + 2560;                // [64][40]
    unsigned short* pH  = qH;                       // P [64][72] overlays q|k

    const float SC = 0.17677669529663687f;
    int colbase[6] = {32 * h, 32 * h + 16, 96 + 32 * h, 96 + 32 * h + 16,
                      192 + 32 * h, 192 + 32 * h + 16};
#pragma unroll
    for (int grp = 0; grp < 2; ++grp) {
        bfv8 wS[3][3];
        f32x4 bS[3];
#pragma unroll
        for (int q3 = 0; q3 < 3; ++q3) {
            int c = colbase[grp * 3 + q3] + rlo;
            wS[q3][0] = ldb8(qkvwb + (size_t)c * 96 + g4 * 8);
            wS[q3][1] = ldb8(qkvwb + (size_t)c * 96 + 32 + g4 * 8);
            wS[q3][2] = ldb8(qkvwb + (size_t)c * 96 + 64 + g4 * 8);
            bS[q3] = *(const f32x4*)(qkvb + colbase[grp * 3 + q3] + g4 * 4);
        }
#pragma unroll
        for (int q3 = 0; q3 < 3; ++q3) {
            int nt = grp * 3 + q3;
#pragma unroll
            for (int mt = 0; mt < 4; ++mt) {
                f32x4 acc = {0.f, 0.f, 0.f, 0.f};
                acc = __builtin_amdgcn_mfma_f32_16x16x32_bf16(wS[q3][0], a[mt][0], acc, 0, 0, 0);
                acc = __builtin_amdgcn_mfma_f32_16x16x32_bf16(wS[q3][1], a[mt][1], acc, 0, 0, 0);
                acc = __builtin_amdgcn_mfma_f32_16x16x32_bf16(wS[q3][2], a[mt][2], acc, 0, 0, 0);
                int token = mt * 16 + rlo;
                if (nt < 2) {
                    f32x4 v = (acc + bS[q3]) * SC;
                    stb4(qH + token * 40 + nt * 16 + g4 * 4, v);
                } else if (nt < 4) {
                    f32x4 v = acc + bS[q3];
                    stb4(kH + token * 40 + (nt - 2) * 16 + g4 * 4, v);
                } else {
#pragma unroll
                    for (int r = 0; r < 4; ++r)  // V^T: 4 d-rows, same token col
                        vtH[((nt - 4) * 16 + g4 * 4 + r) * 72 + token] =
                            f2bn(acc[r] + bS[q3][r]);
                }
            }
        }
    }
    vtH[32 * 72 + lane] = 0x3F80;  // ones row for row-sum via MFMA

    // ---- phase 2: attention (swapped QK: A=keys, B=queries) ----
    bfv8 qf[4], kf[4];
#pragma unroll
    for (int t = 0; t < 4; ++t) {
        qf[t] = ldb8(qH + (t * 16 + rlo) * 40 + g4 * 8);
        kf[t] = ldb8(kH + (t * 16 + rlo) * 40 + g4 * 8);
    }
    f32x4 s[4][4];  // lane: query=rlo, keys g4*4+r
#pragma unroll
    for (int mt = 0; mt < 4; ++mt)
#pragma unroll
        for (int nt = 0; nt < 4; ++nt) {
            f32x4 acc0 = {0.f, 0.f, 0.f, 0.f};
            s[mt][nt] = __builtin_amdgcn_mfma_f32_16x16x32_bf16(kf[nt], qf[mt], acc0, 0, 0, 0);
        }
    int type = ((wi == 31) ? 2 : 0) | ((wj == 31) ? 1 : 0);
    const float* crow = cmb + ((size_t)(type * 3 + h) << 12);
#pragma unroll
    for (int mt = 0; mt < 4; ++mt) {
        int query = mt * 16 + rlo;
        const float* cr = crow + query * 64;
#pragma unroll
        for (int nt = 0; nt < 4; ++nt) {
            f32x4 cv = *(const f32x4*)(cr + nt * 16 + g4 * 4);
            f32x4 p;
#pragma unroll
            for (int r = 0; r < 4; ++r) p[r] = __expf(s[mt][nt][r] + cv[r]);
            stb4(pH + query * 72 + nt * 16 + g4 * 4, p);
        }
    }
    // V^T fragments as A (rows = d); db=2 is the ones/sum tile
    bfv8 vf[2][3];
#pragma unroll
    for (int ks = 0; ks < 2; ++ks)
#pragma unroll
        for (int db = 0; db < 3; ++db)
            vf[ks][db] = ldb8(vtH + (db * 16 + rlo) * 72 + ks * 32 + g4 * 8);
#pragma unroll
    for (int mt = 0; mt < 4; ++mt) {
        bfv8 pa0 = ldb8(pH + (mt * 16 + rlo) * 72 + g4 * 8);
        bfv8 pa1 = ldb8(pH + (mt * 16 + rlo) * 72 + 32 + g4 * 8);
        f32x4 acc[3];
#pragma unroll
        for (int db = 0; db < 3; ++db) {
            acc[db] = {0.f, 0.f, 0.f, 0.f};
            acc[db] = __builtin_amdgcn_mfma_f32_16x16x32_bf16(vf[0][db], pa0, acc[db], 0, 0, 0);
            acc[db] = __builtin_amdgcn_mfma_f32_16x16x32_bf16(vf[1][db], pa1, acc[db], 0, 0, 0);
        }
        float inv = 1.f / __shfl(acc[2][0], rlo);
        int query = mt * 16 + rlo;
        if (query < 49) {
            unsigned short* ob = aout + ((size_t)win * 49 + query) * 96 + h * 32;
#pragma unroll
            for (int db = 0; db < 2; ++db) {
                f32x4 v = acc[db] * inv;
                stb4(ob + db * 16 + g4 * 4, v);
            }
        }
    }
}

// ---------------------------------------------------------------------------
// K2 v7 (best measured, R17): fused proj + residual + LN2 + MLP + residual.
// 128 threads = 2 INDEPENDENT waves (zero barriers); wave-private LDS
// [32][204] (26.1 KB/block -> 6 blocks/CU); xn overlays m1; in-wave lgkmcnt
// ordering only.  xv[2][6] stays in registers across the whole MLP.
__global__ __launch_bounds__(128, 3) void k_pm(const unsigned short* __restrict__ aout,
                                               const unsigned short* __restrict__ projwb,
                                               const float* __restrict__ projb,
                                               const float* __restrict__ x,
                                               const float* __restrict__ g2,
                                               const float* __restrict__ be2,
                                               const unsigned short* __restrict__ w1b,
                                               const float* __restrict__ bias1,
                                               const unsigned short* __restrict__ w2b,
                                               const float* __restrict__ bias2,
                                               float* __restrict__ out) {
    __shared__ unsigned short smem[2 * 32 * 204];  // 26.1 KB -> 6 blocks/CU
    int lane = threadIdx.x & 63, wv = threadIdx.x >> 6;  // wv in {0,1}
    int rlo = lane & 15, g4 = lane >> 4;
    size_t tok0 = (size_t)blockIdx.x * 64;
    unsigned short* mw = smem + wv * 6528;  // wave-private [32][204]; xn overlays

    // 2 token tiles per wave
    bfv8 a0[2][3];
    int pix[2];
#pragma unroll
    for (int t = 0; t < 2; ++t) {
        int tt = 2 * wv + t;
        const unsigned short* p = aout + (tok0 + tt * 16 + rlo) * 96 + g4 * 8;
        a0[t][0] = ldb8(p); a0[t][1] = ldb8(p + 32); a0[t][2] = ldb8(p + 64);
        unsigned wt = (unsigned)(tok0 + tt * 16 + rlo);
        unsigned win = wt / 49u, n = wt - win * 49u;
        unsigned b = win >> 10, widx = win & 1023u;
        unsigned wi = widx >> 5, wj = widx & 31u;
        unsigned i = n / 7u, j = n - i * 7u;
        unsigned sr = wi * 7 + i + 3; if (sr >= 224) sr -= 224;
        unsigned sc = wj * 7 + j + 3; if (sc >= 224) sc -= 224;
        pix[t] = (int)(b * 50176u + sr * 224u + sc);
    }

    // ---- phase P: proj (swapped) + residual + LN2 stats; xv stays in regs ----
    f32x4 xv[2][6];
    float rs[2] = {0.f, 0.f}, rq[2] = {0.f, 0.f};
#pragma unroll
    for (int nt = 0; nt < 6; ++nt) {
        int c = nt * 16 + rlo;
        bfv8 b0 = ldb8(projwb + (size_t)c * 96 + g4 * 8);
        bfv8 b1 = ldb8(projwb + (size_t)c * 96 + 32 + g4 * 8);
        bfv8 b2 = ldb8(projwb + (size_t)c * 96 + 64 + g4 * 8);
        f32x4 bv = *(const f32x4*)(projb + nt * 16 + g4 * 4);
#pragma unroll
        for (int t = 0; t < 2; ++t) {
            f32x4 acc = {0.f, 0.f, 0.f, 0.f};
            acc = __builtin_amdgcn_mfma_f32_16x16x32_bf16(b0, a0[t][0], acc, 0, 0, 0);
            acc = __builtin_amdgcn_mfma_f32_16x16x32_bf16(b1, a0[t][1], acc, 0, 0, 0);
            acc = __builtin_amdgcn_mfma_f32_16x16x32_bf16(b2, a0[t][2], acc, 0, 0, 0);
            f32x4 xr = *(const f32x4*)(x + (size_t)pix[t] * 96 + nt * 16 + g4 * 4);
            f32x4 v = acc + bv + xr;
            xv[t][nt] = v;
            rs[t] += v[0] + v[1] + v[2] + v[3];
            rq[t] += v[0] * v[0] + v[1] * v[1] + v[2] * v[2] + v[3] * v[3];
        }
    }
#pragma unroll
    for (int t = 0; t < 2; ++t) {
        float s = rs[t], q = rq[t];
        s += __shfl_xor(s, 16); q += __shfl_xor(q, 16);
        s += __shfl_xor(s, 32); q += __shfl_xor(q, 32);
        float mu = s * (1.f / 96.f);
        float rstd = rsqrtf(q * (1.f / 96.f) - mu * mu + 1e-5f);
#pragma unroll
        for (int nt = 0; nt < 6; ++nt) {
            f32x4 gg = *(const f32x4*)(g2 + nt * 16 + g4 * 4);
            f32x4 bb = *(const f32x4*)(be2 + nt * 16 + g4 * 4);
            f32x4 v;
#pragma unroll
            for (int r = 0; r < 4; ++r) v[r] = (xv[t][nt][r] - mu) * rstd * gg[r] + bb[r];
            stb4(mw + (t * 16 + rlo) * 104 + nt * 16 + g4 * 4, v);  // xn (overlays m1)
        }
    }
    // fc1 B-frags for the wave's 32 rows (from private xn; in-wave lgkmcnt order)
    bfv8 af[2][3];
#pragma unroll
    for (int mt = 0; mt < 2; ++mt)
#pragma unroll
        for (int ks = 0; ks < 3; ++ks)
            af[mt][ks] = ldb8(mw + (mt * 16 + rlo) * 104 + ks * 32 + g4 * 8);

    f32x4 acc2[2][6];
#pragma unroll
    for (int t = 0; t < 2; ++t)
#pragma unroll
        for (int nt = 0; nt < 6; ++nt) acc2[t][nt] = {0.f, 0.f, 0.f, 0.f};

#pragma unroll
    for (int half = 0; half < 2; ++half) {
        // ---- fc1 half: 12 col-tiles (192 cols) -> GELU -> private m1 ----
#pragma unroll
        for (int ct = 0; ct < 12; ++ct) {
            int cb = half * 192 + ct * 16;
            int c = cb + rlo;
            bfv8 b0 = ldb8(w1b + (size_t)c * 96 + g4 * 8);
            bfv8 b1 = ldb8(w1b + (size_t)c * 96 + 32 + g4 * 8);
            bfv8 b2 = ldb8(w1b + (size_t)c * 96 + 64 + g4 * 8);
            f32x4 bv = *(const f32x4*)(bias1 + cb + g4 * 4);
#pragma unroll
            for (int mt = 0; mt < 2; ++mt) {
                f32x4 acc = {0.f, 0.f, 0.f, 0.f};
                acc = __builtin_amdgcn_mfma_f32_16x16x32_bf16(b0, af[mt][0], acc, 0, 0, 0);
                acc = __builtin_amdgcn_mfma_f32_16x16x32_bf16(b1, af[mt][1], acc, 0, 0, 0);
                acc = __builtin_amdgcn_mfma_f32_16x16x32_bf16(b2, af[mt][2], acc, 0, 0, 0);
                f32x4 g;
#pragma unroll
                for (int r = 0; r < 4; ++r) {
                    float v = acc[r] + bv[r];
                    float z = 1.5957691216057308f * (v + 0.044715f * v * v * v);
                    g[r] = v / (1.f + __expf(-z));
                }
                stb4(mw + (mt * 16 + rlo) * 204 + ct * 16 + g4 * 4, g);  // m1 half
            }
        }
        // ---- fc2 half: 6 K-chunks over the private m1 half ----
#pragma unroll
        for (int ks = 0; ks < 6; ++ks) {
            bfv8 am0 = ldb8(mw + (0 * 16 + rlo) * 204 + ks * 32 + g4 * 8);
            bfv8 am1 = ldb8(mw + (1 * 16 + rlo) * 204 + ks * 32 + g4 * 8);
#pragma unroll
            for (int nt = 0; nt < 6; ++nt) {
                bfv8 bw = ldb8(w2b + (size_t)(nt * 16 + rlo) * 384 + half * 192 + ks * 32 + g4 * 8);
                acc2[0][nt] = __builtin_amdgcn_mfma_f32_16x16x32_bf16(bw, am0, acc2[0][nt], 0, 0, 0);
                acc2[1][nt] = __builtin_amdgcn_mfma_f32_16x16x32_bf16(bw, am1, acc2[1][nt], 0, 0, 0);
            }
        }
    }

    // ---- epilogue: out = fc2 + bias2 + x1 (from registers) ----
#pragma unroll
    for (int t = 0; t < 2; ++t)
#pragma unroll
        for (int nt = 0; nt < 6; ++nt) {
            f32x4 bv = *(const f32x4*)(bias2 + nt * 16 + g4 * 4);
            f32x4 ov = acc2[t][nt] + bv + xv[t][nt];
            *(f32x4*)(out + (size_t)pix[t] * 96 + nt * 16 + g4 * 4) = ov;
        }
}

// ---------------------------------------------------------------------------
extern "C" void kernel_launch(void* const* d_in, const int* in_sizes, int n_in,
                              void* d_out, int out_size, void* d_ws, size_t ws_size,
                              hipStream_t stream) {
    const float* x     = (const float*)d_in[0];
    const float* mask  = (const float*)d_in[1];
    const float* n1g   = (const float*)d_in[2];
    const float* n1b   = (const float*)d_in[3];
    const float* qkvw  = (const float*)d_in[4];
    const float* qkvb  = (const float*)d_in[5];
    const float* rpb   = (const float*)d_in[6];
    const float* projw = (const float*)d_in[7];
    const float* projb = (const float*)d_in[8];
    const float* n2g   = (const float*)d_in[9];
    const float* n2b   = (const float*)d_in[10];
    const float* fc1w  = (const float*)d_in[11];
    const float* fc1b  = (const float*)d_in[12];
    const float* fc2w  = (const float*)d_in[13];
    const float* fc2b  = (const float*)d_in[14];

    // ws: aout(bf16) [0,77.07M) ; wb(bf16,221KB) @77070336 ; cmb(fp32,192KB) @77291520
    if (ws_size < 77488128ULL) return;
    char* ws = (char*)d_ws;
    unsigned short* aout = (unsigned short*)ws;
    unsigned short* wb   = (unsigned short*)(ws + 77070336);
    float*          cmb  = (float*)(ws + 77291520);
    float*          out  = (float*)d_out;

    unsigned short* qkvwb  = wb;          // 27648
    unsigned short* projwb = wb + 27648;  // 9216
    unsigned short* fc1wb  = wb + 36864;  // 36864
    unsigned short* fc2wb  = wb + 73728;  // 36864

    k_prep<<<624, 256, 0, stream>>>(qkvw, projw, fc1w, fc2w, rpb, mask, wb, cmb);
    k_attnf<<<8192, 192, 0, stream>>>(x, n1g, n1b, qkvwb, qkvb, cmb, aout);
    k_pm<<<T / 64, 128, 0, stream>>>(aout, projwb, projb, x, n2g, n2b,
                                     fc1wb, fc1b, fc2wb, fc2b, out);
}